// Round 2
// baseline (432.471 us; speedup 1.0000x reference)
//
#include <hip/hip_runtime.h>
#include <hip/hip_bf16.h>

#define B_ 16
#define T_ 12
#define N_ 2048
#define C_ 64
#define NW_ 10
#define K_ 6144  // WIN*N

typedef __attribute__((ext_vector_type(8))) short bf16x8;
typedef __attribute__((ext_vector_type(4))) float f32x4;

__device__ __forceinline__ unsigned short f2bf(float f) {
  union { float f; unsigned int u; } v; v.f = f;
  unsigned int u = v.u;
  return (unsigned short)((u + 0x7FFFu + ((u >> 16) & 1u)) >> 16);  // RNE
}

// async global->LDS, 16B per lane. LDS dest is wave-uniform base + lane*16.
__device__ __forceinline__ void gload16(const void* g, void* l) {
  __builtin_amdgcn_global_load_lds(
      (const __attribute__((address_space(1))) unsigned int*)g,
      (__attribute__((address_space(3))) unsigned int*)l, 16, 0, 0);
}

// ---------------- prep: x = data + temb + semb -> bf16, layout [b][t][c][n] ----------------
__global__ __launch_bounds__(256) void prep_x(const float* __restrict__ data,
                                              const float* __restrict__ temb,
                                              const float* __restrict__ semb,
                                              unsigned short* __restrict__ xbt) {
  __shared__ __align__(16) unsigned short tile[64][136];  // [c][n_local]
  int blk = blockIdx.x;
  int nt = blk & 15;
  int t = (blk >> 4) % T_;
  int b = blk / (16 * T_);
  int n0 = nt * 128;
  int tid = threadIdx.x;
  int nl = tid >> 1, c0 = (tid & 1) * 32;
  int n = n0 + nl;
  const float* drow = data + ((size_t)(b * T_ + t) * N_ + n) * C_;
  const float* trow = temb + t * C_;
  const float* srow = semb + (size_t)n * C_;
  for (int cc = 0; cc < 32; cc += 4) {
    float4 v = *(const float4*)(drow + c0 + cc);
    float4 te = *(const float4*)(trow + c0 + cc);
    float4 se = *(const float4*)(srow + c0 + cc);
    tile[c0 + cc + 0][nl] = f2bf(v.x + te.x + se.x);
    tile[c0 + cc + 1][nl] = f2bf(v.y + te.y + se.y);
    tile[c0 + cc + 2][nl] = f2bf(v.z + te.z + se.z);
    tile[c0 + cc + 3][nl] = f2bf(v.w + te.w + se.w);
  }
  __syncthreads();
  unsigned short* xrow = xbt + (size_t)(b * T_ + t) * C_ * N_;
  for (int it = 0; it < 4; ++it) {
    int p = it * 256 + tid;
    int c = p >> 4, ng = p & 15;
    uint4 v = *(const uint4*)&tile[c][ng * 8];
    *(uint4*)(xrow + (size_t)c * N_ + n0 + ng * 8) = v;
  }
}

// ---------------- prep: adj_mid rows [N..2N) -> bf16 [m][k] ----------------
__global__ __launch_bounds__(256) void prep_adj(const float* __restrict__ adj,
                                                unsigned short* __restrict__ adjb) {
  size_t i = ((size_t)blockIdx.x * 256 + threadIdx.x) * 8;
  const float* src = adj + (size_t)N_ * K_ + i;
  float4 a = *(const float4*)src;
  float4 b4 = *(const float4*)(src + 4);
  union { unsigned short s[8]; uint4 v; } pk;
  pk.s[0] = f2bf(a.x);  pk.s[1] = f2bf(a.y);  pk.s[2] = f2bf(a.z);  pk.s[3] = f2bf(a.w);
  pk.s[4] = f2bf(b4.x); pk.s[5] = f2bf(b4.y); pk.s[6] = f2bf(b4.z); pk.s[7] = f2bf(b4.w);
  *(uint4*)(adjb + i) = pk.v;
}

// ---------------- prep: W -> bf16 transposed [w][f][d][c] ----------------
__global__ __launch_bounds__(256) void prep_w(const float* __restrict__ W,
                                              unsigned short* __restrict__ wbt) {
  int idx = blockIdx.x * 256 + threadIdx.x;
  int c = idx & 63;
  int d = (idx >> 6) & 127;
  int wf = idx >> 13;
  float v = W[((size_t)wf * 64 + c) * 128 + d];
  wbt[idx] = f2bf(v);
}

// ---------------- main GEMM: dual-window, t'-major, BM=256 ----------------
// block: bm = bid&7 (256 rows), wp = bid>>3 -> b = wp/5, w0 = (wp%5)*2.
// acc[g][i][j] over g=2 windows, 64x64 per wave, 4 waves.
__global__ __launch_bounds__(256, 2) void gemm_agg(const unsigned short* __restrict__ adjb,
                                                   const unsigned short* __restrict__ xbt,
                                                   unsigned short* __restrict__ aggb) {
  __shared__ __align__(16) unsigned short sA[256 * 64];     // [m][k], chunk-swizzled, 32KB
  __shared__ __align__(16) unsigned short sB[2][64 * 64];   // [g][c][k], 8KB each
  int bid = blockIdx.x;
  int bm = bid & 7;
  int wp = bid >> 3;
  int b = wp / 5;
  int w0 = (wp % 5) * 2;
  int tid = threadIdx.x, lane = tid & 63, wid = tid >> 6;
  int lrow8 = lane >> 3, jl = lane & 7;
  int l15 = lane & 15, l4 = lane >> 4;

  f32x4 acc[2][4][4];
  for (int g = 0; g < 2; ++g)
    for (int i = 0; i < 4; ++i)
      for (int j = 0; j < 4; ++j) acc[g][i][j] = (f32x4)0.f;

  const unsigned short* Abase = adjb + (size_t)bm * 256 * K_;

  for (int tp = 0; tp < 3; ++tp) {
    const unsigned short* X0 = xbt + (size_t)(b * T_ + w0 + tp) * C_ * N_;
    const unsigned short* X1 = X0 + (size_t)C_ * N_;  // slice w0+1+tp
    int acol0 = tp * 2048;
    for (int k0 = 0; k0 < 2048; k0 += 64) {
      __syncthreads();
      // stage A: 32 chunks of 1KB, swizzled source (LDS[row][j] = global j^(row&7))
      for (int ci = 0; ci < 8; ++ci) {
        int chunk = wid * 8 + ci;
        int row = chunk * 8 + lrow8;
        int jg = jl ^ (row & 7);
        gload16(Abase + (size_t)row * K_ + acol0 + k0 + jg * 8, &sA[chunk * 512]);
      }
      // stage B: 2 windows x 8 chunks
      for (int ci = 0; ci < 4; ++ci) {
        int chunk = wid * 4 + ci;           // 0..15
        int g = chunk >> 3, cg = chunk & 7;
        int crow = cg * 8 + lrow8;
        int jg = jl ^ (crow & 7);
        const unsigned short* Xs = g ? X1 : X0;
        gload16(Xs + (size_t)crow * N_ + k0 + jg * 8, &sB[g][cg * 512]);
      }
      __syncthreads();
      for (int kk = 0; kk < 2; ++kk) {
        int gchunk = kk * 4 + l4;
        bf16x8 af[4];
        for (int i = 0; i < 4; ++i) {
          int row = wid * 64 + i * 16 + l15;
          int ch = gchunk ^ (row & 7);
          af[i] = *(const bf16x8*)&sA[row * 64 + ch * 8];
        }
        for (int g = 0; g < 2; ++g) {
          bf16x8 bfr[4];
          for (int j = 0; j < 4; ++j) {
            int row = j * 16 + l15;
            int ch = gchunk ^ (row & 7);
            bfr[j] = *(const bf16x8*)&sB[g][row * 64 + ch * 8];
          }
          for (int i = 0; i < 4; ++i)
            for (int j = 0; j < 4; ++j)
              acc[g][i][j] = __builtin_amdgcn_mfma_f32_16x16x32_bf16(af[i], bfr[j], acc[g][i][j], 0, 0, 0);
        }
      }
    }
  }
  // write agg as bf16 [bw][n][c] for both windows
  for (int g = 0; g < 2; ++g) {
    unsigned short* Obase = aggb + (size_t)((b * NW_ + w0 + g) * N_) * C_;
    for (int i = 0; i < 4; ++i)
      for (int j = 0; j < 4; ++j)
        for (int r = 0; r < 4; ++r) {
          int n = bm * 256 + wid * 64 + i * 16 + l4 * 4 + r;
          int c = j * 16 + l15;
          Obase[(size_t)n * C_ + c] = f2bf(acc[g][i][j][r]);
        }
  }
}

// ---------------- epilogue: pre = agg @ W[w,f] + b; glu; max over f ----------------
__global__ __launch_bounds__(256) void glu_out(const unsigned short* __restrict__ aggb,
                                               const unsigned short* __restrict__ wbt,
                                               const float* __restrict__ bias,
                                               float* __restrict__ out) {
  __shared__ __align__(16) unsigned short sW[3 * 128 * 64];  // [f*128+d][c], swizzled
  int bn = blockIdx.x, bw = blockIdx.y;
  int w = bw % NW_;
  int tid = threadIdx.x, lane = tid & 63, wid = tid >> 6;
  int lrow8 = lane >> 3, jl = lane & 7;
  int l15 = lane & 15, l4 = lane >> 4;
  const unsigned short* Wsrc = wbt + (size_t)w * 3 * 128 * 64;
  for (int ci = 0; ci < 12; ++ci) {
    int chunk = wid * 12 + ci;
    int row = chunk * 8 + lrow8;
    int jg = jl ^ (row & 7);
    gload16(Wsrc + (size_t)row * 64 + jg * 8, &sW[chunk * 512]);
  }
  const unsigned short* Abase = aggb + ((size_t)bw * N_ + bn * 128 + wid * 32) * C_;
  bf16x8 af[2][2];
  for (int i = 0; i < 2; ++i)
    for (int kh = 0; kh < 2; ++kh)
      af[i][kh] = *(const bf16x8*)(Abase + (size_t)(i * 16 + l15) * C_ + kh * 32 + l4 * 8);
  __syncthreads();

  float omax[2][4][4];
  for (int i = 0; i < 2; ++i)
    for (int j = 0; j < 4; ++j)
      for (int r = 0; r < 4; ++r) omax[i][j][r] = -INFINITY;

  for (int f = 0; f < 3; ++f) {
    f32x4 acc[2][8];
    for (int i = 0; i < 2; ++i)
      for (int j = 0; j < 8; ++j) acc[i][j] = (f32x4)0.f;
    for (int kh = 0; kh < 2; ++kh) {
      int gchunk = kh * 4 + l4;
      for (int j = 0; j < 8; ++j) {
        int row = f * 128 + j * 16 + l15;
        int ch = gchunk ^ (row & 7);
        bf16x8 bfr = *(const bf16x8*)&sW[row * 64 + ch * 8];
        for (int i = 0; i < 2; ++i)
          acc[i][j] = __builtin_amdgcn_mfma_f32_16x16x32_bf16(af[i][kh], bfr, acc[i][j], 0, 0, 0);
      }
    }
    for (int j = 0; j < 4; ++j) {
      float bl = bias[(w * 3 + f) * 128 + j * 16 + l15];
      float br = bias[(w * 3 + f) * 128 + 64 + j * 16 + l15];
      for (int i = 0; i < 2; ++i)
        for (int r = 0; r < 4; ++r) {
          float lhs = acc[i][j][r] + bl;
          float rhs = acc[i][j + 4][r] + br;
          float g = lhs / (1.f + __expf(-rhs));
          omax[i][j][r] = fmaxf(omax[i][j][r], g);
        }
    }
  }
  float* Obase = out + ((size_t)bw * N_ + bn * 128 + wid * 32) * C_;
  for (int i = 0; i < 2; ++i)
    for (int j = 0; j < 4; ++j)
      for (int r = 0; r < 4; ++r)
        Obase[(size_t)(i * 16 + l4 * 4 + r) * C_ + j * 16 + l15] = omax[i][j][r];
}

extern "C" void kernel_launch(void* const* d_in, const int* in_sizes, int n_in,
                              void* d_out, int out_size, void* d_ws, size_t ws_size,
                              hipStream_t stream) {
  const float* data = (const float*)d_in[0];
  const float* adj  = (const float*)d_in[1];
  const float* temb = (const float*)d_in[2];
  const float* semb = (const float*)d_in[3];
  const float* W    = (const float*)d_in[4];
  const float* bias = (const float*)d_in[5];
  float* out = (float*)d_out;

  char* ws = (char*)d_ws;
  unsigned short* xbt  = (unsigned short*)ws;               // 50,331,648 B
  unsigned short* adjb = (unsigned short*)(ws + 50331648);  // 25,165,824 B
  unsigned short* wbt  = (unsigned short*)(ws + 75497472);  //    491,520 B
  unsigned short* aggb = (unsigned short*)(ws + 75988992);  // 41,943,040 B

  hipLaunchKernelGGL(prep_x,   dim3(16 * T_ * B_), dim3(256), 0, stream, data, temb, semb, xbt);
  hipLaunchKernelGGL(prep_adj, dim3(6144),         dim3(256), 0, stream, adj, adjb);
  hipLaunchKernelGGL(prep_w,   dim3(960),          dim3(256), 0, stream, W, wbt);
  hipLaunchKernelGGL(gemm_agg, dim3(640),          dim3(256), 0, stream, adjb, xbt, aggb);
  hipLaunchKernelGGL(glu_out,  dim3(16, 160),      dim3(256), 0, stream, aggb, wbt, bias, out);
}

// Round 3
// 396.327 us; speedup vs baseline: 1.0912x; 1.0912x over previous
//
#include <hip/hip_runtime.h>
#include <hip/hip_bf16.h>

#define B_ 16
#define T_ 12
#define N_ 2048
#define C_ 64
#define NW_ 10
#define K_ 6144  // WIN*N

typedef __attribute__((ext_vector_type(8))) short bf16x8;
typedef __attribute__((ext_vector_type(4))) float f32x4;

__device__ __forceinline__ unsigned short f2bf(float f) {
  union { float f; unsigned int u; } v; v.f = f;
  unsigned int u = v.u;
  return (unsigned short)((u + 0x7FFFu + ((u >> 16) & 1u)) >> 16);  // RNE
}

__device__ __forceinline__ void gload16(const void* g, void* l) {
  __builtin_amdgcn_global_load_lds(
      (const __attribute__((address_space(1))) unsigned int*)g,
      (__attribute__((address_space(3))) unsigned int*)l, 16, 0, 0);
}

template<int N>
__device__ __forceinline__ void vmw() {
  if constexpr (N == 8)      asm volatile("s_waitcnt vmcnt(8)" ::: "memory");
  else if constexpr (N == 6) asm volatile("s_waitcnt vmcnt(6)" ::: "memory");
  else if constexpr (N == 4) asm volatile("s_waitcnt vmcnt(4)" ::: "memory");
  else if constexpr (N == 3) asm volatile("s_waitcnt vmcnt(3)" ::: "memory");
  else                       asm volatile("s_waitcnt vmcnt(0)" ::: "memory");
}
__device__ __forceinline__ void lgkm0_fence() {
  asm volatile("s_waitcnt lgkmcnt(0)" ::: "memory");
  __builtin_amdgcn_sched_barrier(0);
}

// ---------------- prep: x = data + temb + semb -> bf16, layout [b][t][c][n] ----------------
__global__ __launch_bounds__(256) void prep_x(const float* __restrict__ data,
                                              const float* __restrict__ temb,
                                              const float* __restrict__ semb,
                                              unsigned short* __restrict__ xbt) {
  __shared__ __align__(16) unsigned short tile[64][136];
  int blk = blockIdx.x;
  int nt = blk & 15;
  int t = (blk >> 4) % T_;
  int b = blk / (16 * T_);
  int n0 = nt * 128;
  int tid = threadIdx.x;
  int nl = tid >> 1, c0 = (tid & 1) * 32;
  int n = n0 + nl;
  const float* drow = data + ((size_t)(b * T_ + t) * N_ + n) * C_;
  const float* trow = temb + t * C_;
  const float* srow = semb + (size_t)n * C_;
  for (int cc = 0; cc < 32; cc += 4) {
    float4 v = *(const float4*)(drow + c0 + cc);
    float4 te = *(const float4*)(trow + c0 + cc);
    float4 se = *(const float4*)(srow + c0 + cc);
    tile[c0 + cc + 0][nl] = f2bf(v.x + te.x + se.x);
    tile[c0 + cc + 1][nl] = f2bf(v.y + te.y + se.y);
    tile[c0 + cc + 2][nl] = f2bf(v.z + te.z + se.z);
    tile[c0 + cc + 3][nl] = f2bf(v.w + te.w + se.w);
  }
  __syncthreads();
  unsigned short* xrow = xbt + (size_t)(b * T_ + t) * C_ * N_;
  for (int it = 0; it < 4; ++it) {
    int p = it * 256 + tid;
    int c = p >> 4, ng = p & 15;
    uint4 v = *(const uint4*)&tile[c][ng * 8];
    *(uint4*)(xrow + (size_t)c * N_ + n0 + ng * 8) = v;
  }
}

// ---------------- prep: adj_mid rows [N..2N) -> bf16 [m][k] ----------------
__global__ __launch_bounds__(256) void prep_adj(const float* __restrict__ adj,
                                                unsigned short* __restrict__ adjb) {
  size_t i = ((size_t)blockIdx.x * 256 + threadIdx.x) * 8;
  const float* src = adj + (size_t)N_ * K_ + i;
  float4 a = *(const float4*)src;
  float4 b4 = *(const float4*)(src + 4);
  union { unsigned short s[8]; uint4 v; } pk;
  pk.s[0] = f2bf(a.x);  pk.s[1] = f2bf(a.y);  pk.s[2] = f2bf(a.z);  pk.s[3] = f2bf(a.w);
  pk.s[4] = f2bf(b4.x); pk.s[5] = f2bf(b4.y); pk.s[6] = f2bf(b4.z); pk.s[7] = f2bf(b4.w);
  *(uint4*)(adjb + i) = pk.v;
}

// ---------------- prep: W -> bf16 transposed [w][f][d][c] ----------------
__global__ __launch_bounds__(256) void prep_w(const float* __restrict__ W,
                                              unsigned short* __restrict__ wbt) {
  int idx = blockIdx.x * 256 + threadIdx.x;
  int c = idx & 63;
  int d = (idx >> 6) & 127;
  int wf = idx >> 13;
  float v = W[((size_t)wf * 64 + c) * 128 + d];
  wbt[idx] = f2bf(v);
}

// ---------------- main GEMM: 8-wave, BM=128, G=5 windows, counted-vmcnt pipeline --------
// LDS per K-tile buffer (elems): A[kh] @ kh*4096 (8KB each), B[kh] @ 8192+kh*10240 (20KB each)
// 1KB block = 16 rows; slot(row,J) = (row&15)*4 + (J ^ (row&3)); <=2-way bank aliasing (free).
#define BUF_E 28672  // elems per buffer (56KB)
#define NT_ 96

struct SegCtx {
  const unsigned short* Abase;
  const unsigned short* Xbase;   // xbt + (b*T + w0)*C*N
  int lane, wid, rsub, jsrc, l15, l4, lo, wm, wn;
};

__device__ __forceinline__ void stage_group(const SegCtx& s, unsigned short* lds, int t, int kh) {
  unsigned short* buf = lds + (t & 1) * BUF_E;
  int tp = t >> 5;
  int kc = kh * 32 + s.jsrc * 8;
  // A slot: wave wid -> rows [wid*16, +16)
  gload16(s.Abase + (size_t)(s.wid * 16 + s.rsub) * K_ + t * 64 + kc,
          buf + kh * 4096 + s.wid * 512);
  unsigned short* Bdst = buf + 8192 + kh * 10240;
  int xn = (t & 31) * 64 + kc;
  for (int sl = 0; sl < 2; ++sl) {
    int blk = sl * 8 + s.wid;
    int row = blk * 16 + s.rsub;
    int g = row >> 6, cc = row & 63;
    gload16(s.Xbase + ((size_t)((g + tp) * C_) + cc) * N_ + xn, Bdst + blk * 512);
  }
  if (s.wid < 4) {
    int blk = 16 + s.wid;
    int row = blk * 16 + s.rsub;
    int g = row >> 6, cc = row & 63;
    gload16(s.Xbase + ((size_t)((g + tp) * C_) + cc) * N_ + xn, Bdst + blk * 512);
  }
}

__device__ __forceinline__ void frag_loads(const SegCtx& s, unsigned short* lds, int t, int kh,
                                           bf16x8 af[4], bf16x8 bfv[5]) {
  unsigned short* buf = lds + (t & 1) * BUF_E;
  const unsigned short* Ab = buf + kh * 4096;
  const unsigned short* Bb = buf + 8192 + kh * 10240;
#pragma unroll
  for (int r = 0; r < 4; ++r)
    af[r] = *(const bf16x8*)(Ab + (s.wm * 4 + r) * 512 + s.lo);
#pragma unroll
  for (int c = 0; c < 5; ++c)
    bfv[c] = *(const bf16x8*)(Bb + (s.wn * 5 + c) * 512 + s.lo);
}

__device__ __forceinline__ void mfma_block(bf16x8 af[4], bf16x8 bfv[5], f32x4 acc[4][5]) {
  __builtin_amdgcn_s_setprio(1);
#pragma unroll
  for (int r = 0; r < 4; ++r)
#pragma unroll
    for (int c = 0; c < 5; ++c)
      acc[r][c] = __builtin_amdgcn_mfma_f32_16x16x32_bf16(af[r], bfv[c], acc[r][c], 0, 0, 0);
  __builtin_amdgcn_s_setprio(0);
}

__device__ __forceinline__ void vm_steady(const SegCtx& s) {
  if (s.wid < 4) vmw<8>(); else vmw<6>();
}

__device__ void do_seg(const SegCtx& s, unsigned short* lds, f32x4 acc[4][5]) {
#pragma unroll
  for (int r = 0; r < 4; ++r)
#pragma unroll
    for (int c = 0; c < 5; ++c) acc[r][c] = (f32x4)0.f;

  // prologue: [0,k0],[0,k1],[1,k0]
  __builtin_amdgcn_s_barrier();
  __builtin_amdgcn_sched_barrier(0);
  stage_group(s, lds, 0, 0);
  stage_group(s, lds, 0, 1);
  stage_group(s, lds, 1, 0);
  vm_steady(s);
  __builtin_amdgcn_s_barrier();
  __builtin_amdgcn_sched_barrier(0);

  for (int t = 0; t < NT_; ++t) {
    bf16x8 af[4], bfv[5];
    // ---- phase k0 ----
    frag_loads(s, lds, t, 0, af, bfv);
    if (t + 1 < NT_) stage_group(s, lds, t + 1, 1);
    __builtin_amdgcn_s_barrier();
    lgkm0_fence();
    mfma_block(af, bfv, acc);
    if (t < NT_ - 1) vm_steady(s); else vmw<0>();
    __builtin_amdgcn_s_barrier();
    __builtin_amdgcn_sched_barrier(0);
    // ---- phase k1 ----
    frag_loads(s, lds, t, 1, af, bfv);
    if (t + 2 < NT_) stage_group(s, lds, t + 2, 0);
    __builtin_amdgcn_s_barrier();
    lgkm0_fence();
    mfma_block(af, bfv, acc);
    if (t < NT_ - 2) { vm_steady(s); }
    else if (t == NT_ - 2) { if (s.wid < 4) vmw<4>(); else vmw<3>(); }
    if (t < NT_ - 1) {
      __builtin_amdgcn_s_barrier();
      __builtin_amdgcn_sched_barrier(0);
    }
  }
}

__global__ __launch_bounds__(512, 2) void gemm_agg(const unsigned short* __restrict__ adjb,
                                                   const unsigned short* __restrict__ xbt,
                                                   unsigned short* __restrict__ aggb) {
  __shared__ __align__(16) unsigned short lds[2 * BUF_E];  // 112KB
  int bid = blockIdx.x;
  int b = (bid & 7) + 8 * (bid >> 7);   // XCD-grouped: same-b blocks share an XCD's L2
  int bm = (bid >> 3) & 15;
  int tid = threadIdx.x;
  SegCtx s;
  s.lane = tid & 63; s.wid = tid >> 6;
  s.rsub = s.lane >> 2;
  s.jsrc = (s.lane & 3) ^ (s.rsub & 3);
  s.l15 = s.lane & 15; s.l4 = s.lane >> 4;
  s.lo = ((s.l15 << 2) + (s.l4 ^ (s.lane & 3))) << 3;
  s.wm = s.wid >> 2; s.wn = s.wid & 3;
  s.Abase = adjb + (size_t)bm * 128 * K_;

  f32x4 acc[4][5];
  for (int w0 = 0; w0 <= 5; w0 += 5) {
    s.Xbase = xbt + ((size_t)b * T_ + w0) * C_ * N_;
    do_seg(s, lds, acc);
    // C-write: bf16 agg [bw][n][c]
    unsigned short* Ob0 = aggb + (size_t)(b * NW_ + w0) * N_ * C_;
#pragma unroll
    for (int c = 0; c < 5; ++c) {
      int col = s.wn * 80 + c * 16 + s.l15;
      int g = col >> 6, cw = col & 63;
      unsigned short* Ob = Ob0 + (size_t)g * N_ * C_ + cw;
#pragma unroll
      for (int r = 0; r < 4; ++r) {
        int n0 = bm * 128 + s.wm * 64 + r * 16 + s.l4 * 4;
#pragma unroll
        for (int q = 0; q < 4; ++q)
          Ob[(size_t)(n0 + q) * C_] = f2bf(acc[r][c][q]);
      }
    }
  }
}

// ---------------- epilogue: pre = agg @ W[w,f] + b; glu; max over f ----------------
__global__ __launch_bounds__(256) void glu_out(const unsigned short* __restrict__ aggb,
                                               const unsigned short* __restrict__ wbt,
                                               const float* __restrict__ bias,
                                               float* __restrict__ out) {
  __shared__ __align__(16) unsigned short sW[3 * 128 * 64];
  int bn = blockIdx.x, bw = blockIdx.y;
  int w = bw % NW_;
  int tid = threadIdx.x, lane = tid & 63, wid = tid >> 6;
  int lrow8 = lane >> 3, jl = lane & 7;
  int l15 = lane & 15, l4 = lane >> 4;
  const unsigned short* Wsrc = wbt + (size_t)w * 3 * 128 * 64;
  for (int ci = 0; ci < 12; ++ci) {
    int chunk = wid * 12 + ci;
    int row = chunk * 8 + lrow8;
    int jg = jl ^ (row & 7);
    gload16(Wsrc + (size_t)row * 64 + jg * 8, &sW[chunk * 512]);
  }
  const unsigned short* Abase = aggb + ((size_t)bw * N_ + bn * 128 + wid * 32) * C_;
  bf16x8 af[2][2];
  for (int i = 0; i < 2; ++i)
    for (int kh = 0; kh < 2; ++kh)
      af[i][kh] = *(const bf16x8*)(Abase + (size_t)(i * 16 + l15) * C_ + kh * 32 + l4 * 8);
  __syncthreads();

  float omax[2][4][4];
  for (int i = 0; i < 2; ++i)
    for (int j = 0; j < 4; ++j)
      for (int r = 0; r < 4; ++r) omax[i][j][r] = -INFINITY;

  for (int f = 0; f < 3; ++f) {
    f32x4 acc[2][8];
    for (int i = 0; i < 2; ++i)
      for (int j = 0; j < 8; ++j) acc[i][j] = (f32x4)0.f;
    for (int kh = 0; kh < 2; ++kh) {
      int gchunk = kh * 4 + l4;
      for (int j = 0; j < 8; ++j) {
        int row = f * 128 + j * 16 + l15;
        int ch = gchunk ^ (row & 7);
        bf16x8 bfr = *(const bf16x8*)&sW[row * 64 + ch * 8];
        for (int i = 0; i < 2; ++i)
          acc[i][j] = __builtin_amdgcn_mfma_f32_16x16x32_bf16(af[i][kh], bfr, acc[i][j], 0, 0, 0);
      }
    }
    for (int j = 0; j < 4; ++j) {
      float bl = bias[(w * 3 + f) * 128 + j * 16 + l15];
      float br = bias[(w * 3 + f) * 128 + 64 + j * 16 + l15];
      for (int i = 0; i < 2; ++i)
        for (int r = 0; r < 4; ++r) {
          float lhs = acc[i][j][r] + bl;
          float rhs = acc[i][j + 4][r] + br;
          float g = lhs / (1.f + __expf(-rhs));
          omax[i][j][r] = fmaxf(omax[i][j][r], g);
        }
    }
  }
  float* Obase = out + ((size_t)bw * N_ + bn * 128 + wid * 32) * C_;
  for (int i = 0; i < 2; ++i)
    for (int j = 0; j < 4; ++j)
      for (int r = 0; r < 4; ++r)
        Obase[(size_t)(i * 16 + l4 * 4 + r) * C_ + j * 16 + l15] = omax[i][j][r];
}

extern "C" void kernel_launch(void* const* d_in, const int* in_sizes, int n_in,
                              void* d_out, int out_size, void* d_ws, size_t ws_size,
                              hipStream_t stream) {
  const float* data = (const float*)d_in[0];
  const float* adj  = (const float*)d_in[1];
  const float* temb = (const float*)d_in[2];
  const float* semb = (const float*)d_in[3];
  const float* W    = (const float*)d_in[4];
  const float* bias = (const float*)d_in[5];
  float* out = (float*)d_out;

  char* ws = (char*)d_ws;
  unsigned short* xbt  = (unsigned short*)ws;               // 50,331,648 B
  unsigned short* adjb = (unsigned short*)(ws + 50331648);  // 25,165,824 B
  unsigned short* wbt  = (unsigned short*)(ws + 75497472);  //    491,520 B
  unsigned short* aggb = (unsigned short*)(ws + 75988992);  // 41,943,040 B

  hipLaunchKernelGGL(prep_x,   dim3(16 * T_ * B_), dim3(256), 0, stream, data, temb, semb, xbt);
  hipLaunchKernelGGL(prep_adj, dim3(6144),         dim3(256), 0, stream, adj, adjb);
  hipLaunchKernelGGL(prep_w,   dim3(960),          dim3(256), 0, stream, W, wbt);
  hipLaunchKernelGGL(gemm_agg, dim3(256),          dim3(512), 0, stream, adjb, xbt, aggb);
  hipLaunchKernelGGL(glu_out,  dim3(16, 160),      dim3(256), 0, stream, aggb, wbt, bias, out);
}

// Round 5
// 322.874 us; speedup vs baseline: 1.3394x; 1.2275x over previous
//
#include <hip/hip_runtime.h>
#include <hip/hip_bf16.h>

#define B_ 16
#define T_ 12
#define N_ 2048
#define C_ 64
#define NW_ 10
#define K_ 6144  // WIN*N

#define NT2_ 96        // K-tiles of 64
#define ABUF_E 16384   // A elems per K-tile buffer (256x64)
#define BBUF_E 20480   // B elems per K-tile buffer (320x64)
#define BUF2_E 36864   // 72KB per buffer

typedef __attribute__((ext_vector_type(8))) short bf16x8;
typedef __attribute__((ext_vector_type(4))) float f32x4;

__device__ __forceinline__ unsigned short f2bf(float f) {
  union { float f; unsigned int u; } v; v.f = f;
  unsigned int u = v.u;
  return (unsigned short)((u + 0x7FFFu + ((u >> 16) & 1u)) >> 16);  // RNE
}

__device__ __forceinline__ void gload16(const void* g, void* l) {
  __builtin_amdgcn_global_load_lds(
      (const __attribute__((address_space(1))) unsigned int*)g,
      (__attribute__((address_space(3))) unsigned int*)l, 16, 0, 0);
}

template<int N>
__device__ __forceinline__ void vmw() {
  if constexpr (N == 10)     asm volatile("s_waitcnt vmcnt(10)" ::: "memory");
  else if constexpr (N == 8) asm volatile("s_waitcnt vmcnt(8)" ::: "memory");
  else if constexpr (N == 5) asm volatile("s_waitcnt vmcnt(5)" ::: "memory");
  else if constexpr (N == 4) asm volatile("s_waitcnt vmcnt(4)" ::: "memory");
  else                       asm volatile("s_waitcnt vmcnt(0)" ::: "memory");
}
__device__ __forceinline__ void lgkm0_fence() {
  asm volatile("s_waitcnt lgkmcnt(0)" ::: "memory");
  __builtin_amdgcn_sched_barrier(0);
}

// ---- prep: x = data + temb + semb -> bf16, blocked layout ----
// xbt2[(b*T+t)*32 + nb][o(8)][c(64)][e(8)] = x[b][t][n=nb*64+o*8+e][c]
// total elems 25,165,824 -> 3,145,728 threads -> 12288 blocks of 256
__global__ __launch_bounds__(256) void prep_x2(const float* __restrict__ data,
                                               const float* __restrict__ temb,
                                               const float* __restrict__ semb,
                                               unsigned short* __restrict__ xbt2) {
  int idx = blockIdx.x * 256 + threadIdx.x;   // [0, 3145728)
  int q = idx & 511;
  int btnb = idx >> 9;
  int nb = btnb & 31;
  int bt = btnb >> 5;            // b*T + t, < 192
  int t = bt % T_;
  int o = q >> 6, c = q & 63;
  int n0 = nb * 64 + o * 8;
  float te = temb[t * C_ + c];
  union { unsigned short s[8]; uint4 v; } pk;
#pragma unroll
  for (int e = 0; e < 8; ++e) {
    int n = n0 + e;
    float d = data[((size_t)bt * N_ + n) * C_ + c];
    float se = semb[(size_t)n * C_ + c];
    pk.s[e] = f2bf(d + te + se);
  }
  *(uint4*)(xbt2 + (size_t)idx * 8) = pk.v;
}

// ---- prep: adj_mid rows [N..2N) -> k-major slot layout ----
// adjb2[(bm*96+t)*2048 + (rg*8+o)*16 + r] (16B slots) = adj_mid[m=bm*256+rg*16+r][k=t*64+o*8 ..+8]
__global__ __launch_bounds__(256) void prep_adj2(const float* __restrict__ adj,
                                                 unsigned short* __restrict__ adjb2) {
  int idx = blockIdx.x * 256 + threadIdx.x;   // 1572864 total
  int s = idx & 2047;
  int bmt = idx >> 11;           // bm*96 + t
  int t = bmt % NT2_;
  int bm = bmt / NT2_;
  int r = s & 15;
  int o = (s >> 4) & 7;
  int rg = s >> 7;
  int m = bm * 256 + rg * 16 + r;
  int k = t * 64 + o * 8;
  const float* src = adj + ((size_t)(N_ + m)) * K_ + k;
  float4 a = *(const float4*)src;
  float4 b4 = *(const float4*)(src + 4);
  union { unsigned short s8[8]; uint4 v; } pk;
  pk.s8[0] = f2bf(a.x);  pk.s8[1] = f2bf(a.y);  pk.s8[2] = f2bf(a.z);  pk.s8[3] = f2bf(a.w);
  pk.s8[4] = f2bf(b4.x); pk.s8[5] = f2bf(b4.y); pk.s8[6] = f2bf(b4.z); pk.s8[7] = f2bf(b4.w);
  *(uint4*)(adjb2 + (size_t)idx * 8) = pk.v;
}

// ---- prep: W -> bf16 transposed [w][f][d][c] ----
__global__ __launch_bounds__(256) void prep_w(const float* __restrict__ W,
                                              unsigned short* __restrict__ wbt) {
  int idx = blockIdx.x * 256 + threadIdx.x;
  int c = idx & 63;
  int d = (idx >> 6) & 127;
  int wf = idx >> 13;
  float v = W[((size_t)wf * 64 + c) * 128 + d];
  wbt[idx] = f2bf(v);
}

// ---- main GEMM: BM=256, G=5 windows, wave tile 128x80, k-major LDS, counted vmcnt ----
struct SegCtx {
  const unsigned short* Abase;   // adjb2 + bm*96*ABUF_E
  const unsigned short* Xroot;   // xbt2 + (b*T + w0)*32*4096
  int lane, wid, wm, wn, l4, l15, fbase, bOffLane;
};

__device__ __forceinline__ void stage_group(const SegCtx& s, unsigned short* lds, int t, int kh) {
  unsigned short* buf = lds + (t & 1) * BUF2_E;
  int tp = t >> 5, nn = t & 31;
  // A: 2 chunks per wave (rg = wid*2+ci), fully linear copy of pre-permuted adjb2
#pragma unroll
  for (int ci = 0; ci < 2; ++ci) {
    int rg = s.wid * 2 + ci;
    int off = (rg * 128 + kh * 64) * 8;
    gload16(s.Abase + (size_t)t * ABUF_E + off + s.lane * 8, buf + off);
  }
  // B: 20 chunks (cg in 0..19); waves 0-3: 3, waves 4-7: 2
  unsigned short* Bb = buf + ABUF_E;
  const unsigned short* Xr = s.Xroot + ((size_t)tp * 32 + nn) * 4096;
  int c0 = (s.wid < 4) ? s.wid * 3 : 12 + (s.wid - 4) * 2;
  int nc = (s.wid < 4) ? 3 : 2;
  for (int ci = 0; ci < nc; ++ci) {
    int cg = c0 + ci;
    gload16(Xr + (size_t)(cg >> 2) * 131072 + kh * 2048 + (cg & 3) * 128 + s.bOffLane,
            Bb + cg * 1024 + kh * 512);
  }
}

__device__ __forceinline__ void frag_loads(const SegCtx& s, unsigned short* lds, int t, int kk,
                                           bf16x8 af[8], bf16x8 bfv[5]) {
  unsigned short* buf = lds + (t & 1) * BUF2_E;
  const unsigned short* Ab = buf;
  const unsigned short* Bb = buf + ABUF_E;
#pragma unroll
  for (int i = 0; i < 8; ++i)
    af[i] = *(const bf16x8*)(Ab + (s.wm * 8 + i) * 1024 + kk * 512 + s.fbase);
#pragma unroll
  for (int c = 0; c < 5; ++c)
    bfv[c] = *(const bf16x8*)(Bb + (s.wn * 5 + c) * 1024 + kk * 512 + s.fbase);
}

__device__ __forceinline__ void mfma_block(bf16x8 af[8], bf16x8 bfv[5], f32x4 acc[8][5]) {
  __builtin_amdgcn_s_setprio(1);
#pragma unroll
  for (int i = 0; i < 8; ++i)
#pragma unroll
    for (int c = 0; c < 5; ++c)
      acc[i][c] = __builtin_amdgcn_mfma_f32_16x16x32_bf16(af[i], bfv[c], acc[i][c], 0, 0, 0);
  __builtin_amdgcn_s_setprio(0);
}

__device__ __forceinline__ void vm_steady(const SegCtx& s) {
  if (s.wid < 4) vmw<10>(); else vmw<8>();
}

__global__ __launch_bounds__(512, 2) void gemm_agg(const unsigned short* __restrict__ adjb2,
                                                   const unsigned short* __restrict__ xbt2,
                                                   unsigned short* __restrict__ aggb) {
  __shared__ __align__(16) unsigned short lds[2 * BUF2_E];  // 144KB
  int bid = blockIdx.x;
  int bm = bid & 7;                 // XCD-resident A slice
  int rest = bid >> 3;
  int seg = rest & 1;
  int b = rest >> 1;
  int w0 = seg * 5;
  int tid = threadIdx.x;
  SegCtx s;
  s.lane = tid & 63; s.wid = tid >> 6;
  s.wm = s.wid >> 2; s.wn = s.wid & 3;
  s.l4 = s.lane >> 4; s.l15 = s.lane & 15;
  s.fbase = s.l4 * 128 + s.l15 * 8;
  s.bOffLane = s.l4 * 512 + s.l15 * 8;
  s.Abase = adjb2 + (size_t)bm * NT2_ * ABUF_E;
  s.Xroot = xbt2 + ((size_t)(b * T_ + w0)) * 32 * 4096;

  f32x4 acc[8][5];
#pragma unroll
  for (int i = 0; i < 8; ++i)
#pragma unroll
    for (int c = 0; c < 5; ++c) acc[i][c] = (f32x4)0.f;

  // prologue
  __builtin_amdgcn_sched_barrier(0);
  stage_group(s, lds, 0, 0);
  stage_group(s, lds, 0, 1);
  stage_group(s, lds, 1, 0);
  vm_steady(s);
  __builtin_amdgcn_s_barrier();
  __builtin_amdgcn_sched_barrier(0);

  for (int t = 0; t < NT2_; ++t) {
    bf16x8 af[8], bfv[5];
    // ---- phase k0 ----
    frag_loads(s, lds, t, 0, af, bfv);
    if (t + 1 < NT2_) stage_group(s, lds, t + 1, 1);
    __builtin_amdgcn_s_barrier();
    lgkm0_fence();
    mfma_block(af, bfv, acc);
    if (t < NT2_ - 1) vm_steady(s); else vmw<0>();
    __builtin_amdgcn_s_barrier();
    __builtin_amdgcn_sched_barrier(0);
    // ---- phase k1 ----
    frag_loads(s, lds, t, 1, af, bfv);
    if (t + 2 < NT2_) stage_group(s, lds, t + 2, 0);
    __builtin_amdgcn_s_barrier();
    lgkm0_fence();
    mfma_block(af, bfv, acc);
    if (t < NT2_ - 2) { vm_steady(s); }
    else if (t == NT2_ - 2) { if (s.wid < 4) vmw<5>(); else vmw<4>(); }
    if (t < NT2_ - 1) {
      __builtin_amdgcn_s_barrier();
      __builtin_amdgcn_sched_barrier(0);
    }
  }

  // C-write: bf16 agg [bw][n][c]
  unsigned short* Ob0 = aggb + (size_t)(b * NW_ + w0) * N_ * C_;
#pragma unroll
  for (int c = 0; c < 5; ++c) {
    int col = s.wn * 80 + c * 16 + s.l15;
    int g = col >> 6, cc = col & 63;
    unsigned short* Ob = Ob0 + (size_t)g * N_ * C_ + cc;
#pragma unroll
    for (int i = 0; i < 8; ++i) {
      int n0 = bm * 256 + s.wm * 128 + i * 16 + s.l4 * 4;
#pragma unroll
      for (int q = 0; q < 4; ++q)
        Ob[(size_t)(n0 + q) * C_] = f2bf(acc[i][c][q]);
    }
  }
}

// ---- epilogue: pre = agg @ W[w,f] + b; glu; max over f ----
__global__ __launch_bounds__(256) void glu_out(const unsigned short* __restrict__ aggb,
                                               const unsigned short* __restrict__ wbt,
                                               const float* __restrict__ bias,
                                               float* __restrict__ out) {
  __shared__ __align__(16) unsigned short sW[3 * 128 * 64];
  int bn = blockIdx.x, bw = blockIdx.y;
  int w = bw % NW_;
  int tid = threadIdx.x, lane = tid & 63, wid = tid >> 6;
  int lrow8 = lane >> 3, jl = lane & 7;
  int l15 = lane & 15, l4 = lane >> 4;
  const unsigned short* Wsrc = wbt + (size_t)w * 3 * 128 * 64;
  for (int ci = 0; ci < 12; ++ci) {
    int chunk = wid * 12 + ci;
    int row = chunk * 8 + lrow8;
    int jg = jl ^ (row & 7);
    gload16(Wsrc + (size_t)row * 64 + jg * 8, &sW[chunk * 512]);
  }
  const unsigned short* Abase = aggb + ((size_t)bw * N_ + bn * 128 + wid * 32) * C_;
  bf16x8 af[2][2];
  for (int i = 0; i < 2; ++i)
    for (int kh = 0; kh < 2; ++kh)
      af[i][kh] = *(const bf16x8*)(Abase + (size_t)(i * 16 + l15) * C_ + kh * 32 + l4 * 8);
  __syncthreads();

  float omax[2][4][4];
  for (int i = 0; i < 2; ++i)
    for (int j = 0; j < 4; ++j)
      for (int r = 0; r < 4; ++r) omax[i][j][r] = -INFINITY;

  for (int f = 0; f < 3; ++f) {
    f32x4 acc[2][8];
    for (int i = 0; i < 2; ++i)
      for (int j = 0; j < 8; ++j) acc[i][j] = (f32x4)0.f;
    for (int kh = 0; kh < 2; ++kh) {
      int gchunk = kh * 4 + l4;
      for (int j = 0; j < 8; ++j) {
        int row = f * 128 + j * 16 + l15;
        int ch = gchunk ^ (row & 7);
        bf16x8 bfr = *(const bf16x8*)&sW[row * 64 + ch * 8];
        for (int i = 0; i < 2; ++i)
          acc[i][j] = __builtin_amdgcn_mfma_f32_16x16x32_bf16(af[i][kh], bfr, acc[i][j], 0, 0, 0);
      }
    }
    for (int j = 0; j < 4; ++j) {
      float bl = bias[(w * 3 + f) * 128 + j * 16 + l15];
      float br = bias[(w * 3 + f) * 128 + 64 + j * 16 + l15];
      for (int i = 0; i < 2; ++i)
        for (int r = 0; r < 4; ++r) {
          float lhs = acc[i][j][r] + bl;
          float rhs = acc[i][j + 4][r] + br;
          float g = lhs / (1.f + __expf(-rhs));
          omax[i][j][r] = fmaxf(omax[i][j][r], g);
        }
    }
  }
  float* Obase = out + ((size_t)bw * N_ + bn * 128 + wid * 32) * C_;
  for (int i = 0; i < 2; ++i)
    for (int j = 0; j < 4; ++j)
      for (int r = 0; r < 4; ++r)
        Obase[(size_t)(i * 16 + l4 * 4 + r) * C_ + j * 16 + l15] = omax[i][j][r];
}

extern "C" void kernel_launch(void* const* d_in, const int* in_sizes, int n_in,
                              void* d_out, int out_size, void* d_ws, size_t ws_size,
                              hipStream_t stream) {
  const float* data = (const float*)d_in[0];
  const float* adj  = (const float*)d_in[1];
  const float* temb = (const float*)d_in[2];
  const float* semb = (const float*)d_in[3];
  const float* W    = (const float*)d_in[4];
  const float* bias = (const float*)d_in[5];
  float* out = (float*)d_out;

  char* ws = (char*)d_ws;
  unsigned short* xbt2  = (unsigned short*)ws;               // 50,331,648 B
  unsigned short* adjb2 = (unsigned short*)(ws + 50331648);  // 25,165,824 B
  unsigned short* wbt   = (unsigned short*)(ws + 75497472);  //    491,520 B
  unsigned short* aggb  = (unsigned short*)(ws + 75988992);  // 41,943,040 B

  hipLaunchKernelGGL(prep_x2,   dim3(12288), dim3(256), 0, stream, data, temb, semb, xbt2);
  hipLaunchKernelGGL(prep_adj2, dim3(6144),  dim3(256), 0, stream, adj, adjb2);
  hipLaunchKernelGGL(prep_w,    dim3(960),   dim3(256), 0, stream, W, wbt);
  hipLaunchKernelGGL(gemm_agg,  dim3(256),   dim3(512), 0, stream, adjb2, xbt2, aggb);
  hipLaunchKernelGGL(glu_out,   dim3(16, 160), dim3(256), 0, stream, aggb, wbt, bias, out);
}